// Round 6
// baseline (184.177 us; speedup 1.0000x reference)
//
#include <hip/hip_runtime.h>
#include <hip/hip_bf16.h>
#include <math.h>

#define BDIM 4
#define SLEN 4096
#define DDIM 1024
#define MROWS (BDIM*SLEN)      // 16384
#define KDIM DDIM              // 1024
#define NCHUNK 64
#define CLEN (SLEN/NCHUNK)     // 64
#define NCH (BDIM*DDIM)        // 4096
#define NKT (KDIM/32)          // 32 K-steps
#define LDSBUF 16384           // one buffer: X 8KB + Wa 4KB + Wx 4KB

typedef __bf16 bf16;
typedef __bf16 bf16x8 __attribute__((ext_vector_type(8)));
typedef float f32x4 __attribute__((ext_vector_type(4)));

__device__ __forceinline__ void gload_lds16(const void* g, void* l) {
  __builtin_amdgcn_global_load_lds(
      (const __attribute__((address_space(1))) unsigned int*)g,
      (__attribute__((address_space(3))) unsigned int*)l, 16, 0, 0);
}

// ---------------- cast f32 -> bf16, 8 elems/thread ----------------
__global__ void cast_bf16_kernel(const float* __restrict__ in, bf16* __restrict__ out, int n8) {
  int i = blockIdx.x * blockDim.x + threadIdx.x;
  if (i >= n8) return;
  const float4* p = (const float4*)in;
  float4 v0 = p[2*i], v1 = p[2*i+1];
  bf16x8 o;
  o[0] = (bf16)v0.x; o[1] = (bf16)v0.y; o[2] = (bf16)v0.z; o[3] = (bf16)v0.w;
  o[4] = (bf16)v1.x; o[5] = (bf16)v1.y; o[6] = (bf16)v1.z; o[7] = (bf16)v1.w;
  ((bf16x8*)out)[i] = o;
}

// ---------------- klam[h] = -C * softplus(-Lam[h]) ----------------
__global__ void klam_kernel(const float* __restrict__ Lam, float* __restrict__ klam) {
  int h = blockIdx.x * blockDim.x + threadIdx.x;
  if (h < DDIM) klam[h] = -8.0f * log1pf(__expf(-Lam[h]));
}

// ---------------- dual-weight GEMM + gate epilogue ----------------
// Block tile 128(M) x 64(N), BK=32, 4 waves of 64x32-dual each.
// T4 counted-vmcnt pipeline: 3 LDS buffers, 2 tiles in flight,
// s_waitcnt vmcnt(4) (never 0 in-loop) + ONE raw s_barrier per K-step.
// Safety argument for single barrier: a wave passing iter t's barrier has
// completed its iter t-1 ds_reads (compiler lgkm wait before MFMA), so
// staging tile t+2 into buf[(t+2)%3] (last read at iter t-1) is race-free.
__global__ __launch_bounds__(256, 3) void gemm_gates_kernel(
    const bf16* __restrict__ xb, const bf16* __restrict__ wab, const bf16* __restrict__ wxb,
    const float* __restrict__ ba, const float* __restrict__ bx,
    const float* __restrict__ klam, float* __restrict__ Aarr, float* __restrict__ Barr)
{
  __shared__ char smem[3*LDSBUF];   // 48 KB

  const int tid  = threadIdx.x;
  const int wave = tid >> 6, lane = tid & 63;
  const int wm = wave >> 1, wn = wave & 1;       // M split 2x64, N split 2x32

  // XCD-bijective swizzle: 2048 blocks, 8 XCDs, 256 each.
  const int orig  = blockIdx.x;
  const int newid = (orig & 7) * 256 + (orig >> 3);
  const int m0 = (newid >> 4) * 128;
  const int h0 = (newid & 15) * 64;

  f32x4 accA[4][2], accX[4][2];
  #pragma unroll
  for (int i = 0; i < 4; i++)
    #pragma unroll
    for (int j = 0; j < 2; j++) { accA[i][j] = (f32x4)0.0f; accX[i][j] = (f32x4)0.0f; }

  // staging: LDS slot tid*16 holds (row = tid>>2, granule kg = (tid&3)^((tid>>4)&3))
  const int srow = tid >> 2;
  const int skc  = (((tid & 3) ^ ((tid >> 4) & 3))) * 8;
  // fragment-read per-lane offset within a 16-row block (1024B), same involution
  const int lroff = (lane & 15) * 64 + (((lane >> 4) ^ ((lane & 15) >> 2)) * 16);

  // per-thread global staging bases (advance 32 elems per K-step)
  const bf16* gx0 = xb  + (size_t)(m0 +      srow) * KDIM + skc;
  const bf16* gx1 = xb  + (size_t)(m0 + 64 + srow) * KDIM + skc;
  const bf16* gwa = wab + (size_t)(h0 +      srow) * KDIM + skc;
  const bf16* gwx = wxb + (size_t)(h0 +      srow) * KDIM + skc;

  auto STAGE = [&](int t, char* nb) {
    const int ko = t * 32;
    gload_lds16(gx0 + ko, nb + tid*16);
    gload_lds16(gx1 + ko, nb + 4096  + tid*16);
    gload_lds16(gwa + ko, nb + 8192  + tid*16);
    gload_lds16(gwx + ko, nb + 12288 + tid*16);
  };

  char* b0 = smem;
  char* b1 = smem + LDSBUF;
  char* b2 = smem + 2*LDSBUF;

  // prologue: 2 tiles in flight (8 outstanding loads)
  STAGE(0, b0);
  STAGE(1, b1);

  char *pc = b0, *pn = b1, *ps = b2;   // current / next / stage-target
  for (int kt = 0; kt < NKT; ++kt) {
    // tile kt landed when (outstanding <= 4): tiles kt,kt+1 in flight -> wait 4.
    if (kt == NKT - 1) { asm volatile("s_waitcnt vmcnt(0)" ::: "memory"); }
    else               { asm volatile("s_waitcnt vmcnt(4)" ::: "memory"); }
    __builtin_amdgcn_s_barrier();          // all waves confirmed their loads
    __builtin_amdgcn_sched_barrier(0);     // pin: no reads hoisted above barrier

    if (kt + 2 < NKT) STAGE(kt + 2, ps);   // issue early; lands ~2 iters later

    bf16x8 af[4], bfa[2], bfx[2];
    #pragma unroll
    for (int mi = 0; mi < 4; mi++)
      af[mi] = *(const bf16x8*)(pc + (wm*4 + mi)*1024 + lroff);
    #pragma unroll
    for (int ni = 0; ni < 2; ni++) {
      bfa[ni] = *(const bf16x8*)(pc + 8192  + (wn*2 + ni)*1024 + lroff);
      bfx[ni] = *(const bf16x8*)(pc + 12288 + (wn*2 + ni)*1024 + lroff);
    }

    __builtin_amdgcn_s_setprio(1);
    #pragma unroll
    for (int mi = 0; mi < 4; mi++)
      #pragma unroll
      for (int ni = 0; ni < 2; ni++) {
        accA[mi][ni] = __builtin_amdgcn_mfma_f32_16x16x32_bf16(af[mi], bfa[ni], accA[mi][ni], 0, 0, 0);
        accX[mi][ni] = __builtin_amdgcn_mfma_f32_16x16x32_bf16(af[mi], bfx[ni], accX[mi][ni], 0, 0, 0);
      }
    __builtin_amdgcn_s_setprio(0);

    char* tmp = pc; pc = pn; pn = ps; ps = tmp;   // rotate buffers
  }

  // epilogue: C/D layout col = lane&15 (h), row = (lane>>4)*4 + j (m)
  #pragma unroll
  for (int mi = 0; mi < 4; mi++) {
    #pragma unroll
    for (int ni = 0; ni < 2; ni++) {
      const int h  = h0 + wn*32 + ni*16 + (lane & 15);
      const int mb = m0 + wm*64 + mi*16 + ((lane >> 4) << 2);
      const float bah = ba[h], bxh = bx[h], kl = klam[h];
      #pragma unroll
      for (int j = 0; j < 4; j++) {
        const int m = mb + j;
        const float ga = accA[mi][ni][j] + bah;
        const float gx = accX[mi][ni][j] + bxh;
        const float rt = 1.0f / (1.0f + __expf(-ga));
        const float it = 1.0f / (1.0f + __expf(-gx));
        const float a  = __expf(kl * rt);
        const float xv = (float)xb[(size_t)m * DDIM + h];
        const float bb = sqrtf(fmaxf(1.0f - a*a, 0.0f)) * (it * xv);
        Aarr[(size_t)m * DDIM + h] = a;
        Barr[(size_t)m * DDIM + h] = bb;
      }
    }
  }
}

// ---------------- chunked scan: phase 1 (per-chunk summaries) ----------------
__global__ void scan1_kernel(const float* __restrict__ Aarr, const float* __restrict__ Barr,
                             float* __restrict__ sA, float* __restrict__ sB) {
  const int ch = blockIdx.x * 256 + threadIdx.x;   // 0..4095 = b*1024 + d
  const int c  = blockIdx.y;                       // chunk
  const int b  = ch >> 10, d = ch & 1023;
  size_t idx = ((size_t)b * SLEN + (size_t)c * CLEN) * DDIM + d;
  float pa = 1.0f, h = 0.0f;
  #pragma unroll 4
  for (int s = 0; s < CLEN; ++s) {
    const float a  = Aarr[idx];
    const float bb = Barr[idx];
    h  = fmaf(a, h, bb);
    pa *= a;
    idx += DDIM;
  }
  sA[c * NCH + ch] = pa;
  sB[c * NCH + ch] = h;
}

// ---------------- phase 2: sequential prefix over chunks ----------------
__global__ void scan2_kernel(const float* __restrict__ sA, const float* __restrict__ sB,
                             float* __restrict__ Hin) {
  const int ch = blockIdx.x * 256 + threadIdx.x;
  float h = 0.0f;
  for (int c = 0; c < NCHUNK; ++c) {
    Hin[c * NCH + ch] = h;
    h = fmaf(sA[c * NCH + ch], h, sB[c * NCH + ch]);
  }
}

// ---------------- phase 3: apply (in place over Barr == d_out) ----------------
__global__ void scan3_kernel(const float* __restrict__ Aarr, const float* __restrict__ Hin,
                             float* __restrict__ y) {
  const int ch = blockIdx.x * 256 + threadIdx.x;
  const int c  = blockIdx.y;
  const int b  = ch >> 10, d = ch & 1023;
  size_t idx = ((size_t)b * SLEN + (size_t)c * CLEN) * DDIM + d;
  float h = Hin[c * NCH + ch];
  #pragma unroll 4
  for (int s = 0; s < CLEN; ++s) {
    const float a  = Aarr[idx];
    const float bb = y[idx];
    h = fmaf(a, h, bb);
    y[idx] = h;
    idx += DDIM;
  }
}

extern "C" void kernel_launch(void* const* d_in, const int* in_sizes, int n_in,
                              void* d_out, int out_size, void* d_ws, size_t ws_size,
                              hipStream_t stream) {
  const float* x   = (const float*)d_in[0];
  const float* Wa  = (const float*)d_in[1];
  const float* Wx  = (const float*)d_in[2];
  const float* ba  = (const float*)d_in[3];
  const float* bx  = (const float*)d_in[4];
  const float* Lam = (const float*)d_in[5];
  float* y = (float*)d_out;

  // workspace layout (bytes): needs 108,007,424 total
  if (ws_size < 108007424ULL) return;  // insufficient scratch; fail cleanly
  char* ws = (char*)d_ws;
  float* Aarr = (float*)(ws);                    // 64 MB: decay a
  bf16*  xb   = (bf16*)(ws + 67108864);          // 32 MB: x in bf16
  bf16*  wab  = (bf16*)(ws + 100663296);         //  2 MB
  bf16*  wxb  = (bf16*)(ws + 102760448);         //  2 MB
  float* klam = (float*)(ws + 104857600);        //  4 KB
  float* sA   = (float*)(ws + 104861696);        //  1 MB
  float* sB   = (float*)(ws + 105910272);        //  1 MB
  float* Hin  = (float*)(ws + 106958848);        //  1 MB
  float* Barr = y;                               // b lives in d_out, transformed in place

  cast_bf16_kernel<<<(MROWS*DDIM/8)/256, 256, 0, stream>>>(x,  xb,  MROWS*DDIM/8);
  cast_bf16_kernel<<<(DDIM*DDIM/8)/256, 256, 0, stream>>>(Wa, wab, DDIM*DDIM/8);
  cast_bf16_kernel<<<(DDIM*DDIM/8)/256, 256, 0, stream>>>(Wx, wxb, DDIM*DDIM/8);
  klam_kernel<<<DDIM/256, 256, 0, stream>>>(Lam, klam);

  // 2048 blocks: (M/128) * (N/64) = 128 * 16
  gemm_gates_kernel<<<2048, 256, 0, stream>>>(xb, wab, wxb, ba, bx, klam, Aarr, Barr);

  dim3 sgrid(NCH/256, NCHUNK);
  scan1_kernel<<<sgrid, 256, 0, stream>>>(Aarr, Barr, sA, sB);
  scan2_kernel<<<NCH/256, 256, 0, stream>>>(sA, sB, Hin);
  scan3_kernel<<<sgrid, 256, 0, stream>>>(Aarr, Hin, y);
}

// Round 8
// 179.925 us; speedup vs baseline: 1.0236x; 1.0236x over previous
//
#include <hip/hip_runtime.h>
#include <hip/hip_bf16.h>
#include <math.h>

#define BDIM 4
#define SLEN 4096
#define DDIM 1024
#define MROWS (BDIM*SLEN)      // 16384
#define KDIM DDIM              // 1024
#define NCHUNK 64
#define CLEN (SLEN/NCHUNK)     // 64
#define NCH (BDIM*DDIM)        // 4096
#define NKT (KDIM/32)          // 32 K-steps
#define LDSBUF 16384           // one buffer: X 8KB (4 tiles) + Wa 4KB + Wx 4KB

typedef __bf16 bf16;
typedef __bf16 bf16x8 __attribute__((ext_vector_type(8)));
typedef float f32x16 __attribute__((ext_vector_type(16)));

__device__ __forceinline__ void gload_lds16(const void* g, void* l) {
  __builtin_amdgcn_global_load_lds(
      (const __attribute__((address_space(1))) unsigned int*)g,
      (__attribute__((address_space(3))) unsigned int*)l, 16, 0, 0);
}

// ---------------- cast f32 -> bf16 with fragment-order tile swizzle ----------
// Output layout: [T][KT] tiles of 2KB; tile = 32 rows x 32 k. Granule (r, j)
// (16B = 8 bf16, k-span j*8..j*8+8) stored at slot j*32 + r within the tile,
// so MFMA 32x32x16 fragment read = base + lane*16 gives row = lane&31,
// k-granule = lane>>5 — exactly the A/B operand layout. Reads stay coalesced
// (4-lane clusters read 128B contiguous); writes permute within 2KB only.
__global__ void cast_swz_kernel(const float* __restrict__ in, bf16* __restrict__ out) {
  const int gid  = blockIdx.x * 256 + threadIdx.x;
  const int tile = gid >> 7, local = gid & 127;
  const int j = local & 3, r = local >> 2;     // coalesced read assignment
  const int T = tile >> 5, KT = tile & 31;     // K fixed = 1024 -> 32 k-tiles
  const float4* src = (const float4*)(in + (size_t)(T*32 + r) * KDIM + KT*32 + j*8);
  float4 v0 = src[0], v1 = src[1];
  bf16x8 o;
  o[0] = (bf16)v0.x; o[1] = (bf16)v0.y; o[2] = (bf16)v0.z; o[3] = (bf16)v0.w;
  o[4] = (bf16)v1.x; o[5] = (bf16)v1.y; o[6] = (bf16)v1.z; o[7] = (bf16)v1.w;
  ((bf16x8*)out)[(size_t)tile * 128 + j*32 + r] = o;   // fragment-order slot
}

// ---------------- klam[h] = -C * softplus(-Lam[h]) ----------------
__global__ void klam_kernel(const float* __restrict__ Lam, float* __restrict__ klam) {
  int h = blockIdx.x * blockDim.x + threadIdx.x;
  if (h < DDIM) klam[h] = -8.0f * log1pf(__expf(-Lam[h]));
}

// ---------------- dual-weight GEMM + gate epilogue (32x32x16 MFMA) ----------
// Block tile 128(M) x 64(N), BK=32, 4 waves of 64x32-dual each.
// Per K-step per wave: 8 ds_read_b128 + 8 MFMA (vs 12+16 with 16x16x32).
// All LDS reads are base + lane*16 (fragment-order) -> zero bank conflicts.
// Pipeline: 3 LDS buffers, 2 tiles in flight, vmcnt(4) counted waits,
// one s_barrier per K-step.
__global__ __launch_bounds__(256, 3) void gemm_gates_kernel(
    const bf16* __restrict__ xb, const bf16* __restrict__ wab, const bf16* __restrict__ wxb,
    const float* __restrict__ ba, const float* __restrict__ bx,
    const float* __restrict__ klam, float* __restrict__ Aarr, float* __restrict__ Barr)
{
  __shared__ char smem[3*LDSBUF];   // 48 KB

  const int tid  = threadIdx.x;
  const int wave = tid >> 6, lane = tid & 63;
  const int wm = wave >> 1, wn = wave & 1;       // M split 2x64, N split 2x32

  // XCD-bijective swizzle: 2048 blocks, 8 XCDs, 256 each.
  const int orig  = blockIdx.x;
  const int newid = (orig & 7) * 256 + (orig >> 3);
  const int m0 = (newid >> 4) * 128;
  const int h0 = (newid & 15) * 64;

  f32x16 accA0 = (f32x16)0.0f, accA1 = (f32x16)0.0f;
  f32x16 accX0 = (f32x16)0.0f, accX1 = (f32x16)0.0f;

  // staging sources (fragment-order global): 1024 elems per KT-tile,
  // 32768 elems per T(row-tile). Thread t stages granule (t&127) of tile (t>>7).
  const int Tb = m0 >> 5;           // first of 4 X row-tiles
  const int Ht = h0 >> 5;           // first of 2 W row-tiles
  const bf16* xsrc0 = xb  + (size_t)(Tb + (tid >> 7)) * 32768 + (tid & 127) * 8;
  const bf16* xsrc1 = xsrc0 + 2 * 32768;
  const bf16* wsrcA = wab + (size_t)(Ht + (tid >> 7)) * 32768 + (tid & 127) * 8;
  const bf16* wsrcX = wxb + (size_t)(Ht + (tid >> 7)) * 32768 + (tid & 127) * 8;

  auto STAGE = [&](int KT, char* nb) {
    gload_lds16(xsrc0 + KT*1024, nb + tid*16);            // X tiles 0,1
    gload_lds16(xsrc1 + KT*1024, nb + 4096  + tid*16);    // X tiles 2,3
    gload_lds16(wsrcA + KT*1024, nb + 8192  + tid*16);    // Wa tiles 0,1
    gload_lds16(wsrcX + KT*1024, nb + 12288 + tid*16);    // Wx tiles 0,1
  };

  // per-wave fragment read offsets (all base + lane*16 -> conflict-free)
  const int awoff  = wm*4096  + lane*16;            // A: tiles wm*2, wm*2+1
  const int bwoffA = 8192  + wn*2048 + lane*16;     // Wa tile wn
  const int bwoffX = 12288 + wn*2048 + lane*16;     // Wx tile wn

  char* b0 = smem;
  char* b1 = smem + LDSBUF;
  char* b2 = smem + 2*LDSBUF;

  STAGE(0, b0);
  STAGE(1, b1);

  char *pc = b0, *pn = b1, *ps = b2;
  for (int kt = 0; kt < NKT; ++kt) {
    if (kt == NKT - 1) { asm volatile("s_waitcnt vmcnt(0)" ::: "memory"); }
    else               { asm volatile("s_waitcnt vmcnt(4)" ::: "memory"); }
    __builtin_amdgcn_s_barrier();
    __builtin_amdgcn_sched_barrier(0);

    if (kt + 2 < NKT) STAGE(kt + 2, ps);

    bf16x8 a00 = *(const bf16x8*)(pc + awoff);            // mt0, k 0..16
    bf16x8 a01 = *(const bf16x8*)(pc + awoff + 1024);     // mt0, k 16..32
    bf16x8 a10 = *(const bf16x8*)(pc + awoff + 2048);     // mt1, k 0..16
    bf16x8 a11 = *(const bf16x8*)(pc + awoff + 3072);     // mt1, k 16..32
    bf16x8 ba0 = *(const bf16x8*)(pc + bwoffA);
    bf16x8 ba1 = *(const bf16x8*)(pc + bwoffA + 1024);
    bf16x8 bx0 = *(const bf16x8*)(pc + bwoffX);
    bf16x8 bx1 = *(const bf16x8*)(pc + bwoffX + 1024);

    __builtin_amdgcn_s_setprio(1);
    accA0 = __builtin_amdgcn_mfma_f32_32x32x16_bf16(a00, ba0, accA0, 0, 0, 0);
    accA1 = __builtin_amdgcn_mfma_f32_32x32x16_bf16(a10, ba0, accA1, 0, 0, 0);
    accX0 = __builtin_amdgcn_mfma_f32_32x32x16_bf16(a00, bx0, accX0, 0, 0, 0);
    accX1 = __builtin_amdgcn_mfma_f32_32x32x16_bf16(a10, bx0, accX1, 0, 0, 0);
    accA0 = __builtin_amdgcn_mfma_f32_32x32x16_bf16(a01, ba1, accA0, 0, 0, 0);
    accA1 = __builtin_amdgcn_mfma_f32_32x32x16_bf16(a11, ba1, accA1, 0, 0, 0);
    accX0 = __builtin_amdgcn_mfma_f32_32x32x16_bf16(a01, bx1, accX0, 0, 0, 0);
    accX1 = __builtin_amdgcn_mfma_f32_32x32x16_bf16(a11, bx1, accX1, 0, 0, 0);
    __builtin_amdgcn_s_setprio(0);

    char* tmp = pc; pc = pn; pn = ps; ps = tmp;
  }

  // epilogue: 32x32 C/D layout: col = lane&31, row = (q&3) + 8*(q>>2) + 4*(lane>>5)
  const int colh = h0 + wn*32 + (lane & 31);
  const float bah = ba[colh], bxh = bx[colh], kl = klam[colh];
  // x reload from swizzled xb: elem = (T*32 + KT)*1024 + (j*32 + r)*8 + e
  const size_t xh = (size_t)(colh >> 5) * 1024 + ((colh >> 3) & 3) * 256 + (colh & 7);

  #pragma unroll
  for (int mt = 0; mt < 2; ++mt) {
    const int mbase = m0 + wm*64 + mt*32;                  // 32-aligned
    const size_t xtb = (size_t)(mbase >> 5) * 32768 + xh;  // + row*8 per elem
    const f32x16 aA = mt ? accA1 : accA0;
    const f32x16 aX = mt ? accX1 : accX0;
    #pragma unroll
    for (int q = 0; q < 16; ++q) {
      const int row = (q & 3) + 8*(q >> 2) + 4*(lane >> 5);
      const int m = mbase + row;
      const float ga = aA[q] + bah;
      const float gx = aX[q] + bxh;
      const float rt = 1.0f / (1.0f + __expf(-ga));
      const float it = 1.0f / (1.0f + __expf(-gx));
      const float a  = __expf(kl * rt);
      const float xv = (float)xb[xtb + (size_t)row * 8];
      const float bb = sqrtf(fmaxf(1.0f - a*a, 0.0f)) * (it * xv);
      Aarr[(size_t)m * DDIM + colh] = a;
      Barr[(size_t)m * DDIM + colh] = bb;
    }
  }
}

// ---------------- chunked scan: phase 1 (per-chunk summaries) ----------------
__global__ void scan1_kernel(const float* __restrict__ Aarr, const float* __restrict__ Barr,
                             float* __restrict__ sA, float* __restrict__ sB) {
  const int ch = blockIdx.x * 256 + threadIdx.x;   // 0..4095 = b*1024 + d
  const int c  = blockIdx.y;                       // chunk
  const int b  = ch >> 10, d = ch & 1023;
  size_t idx = ((size_t)b * SLEN + (size_t)c * CLEN) * DDIM + d;
  float pa = 1.0f, h = 0.0f;
  #pragma unroll 4
  for (int s = 0; s < CLEN; ++s) {
    const float a  = Aarr[idx];
    const float bb = Barr[idx];
    h  = fmaf(a, h, bb);
    pa *= a;
    idx += DDIM;
  }
  sA[c * NCH + ch] = pa;
  sB[c * NCH + ch] = h;
}

// ---------------- phase 2: sequential prefix over chunks ----------------
__global__ void scan2_kernel(const float* __restrict__ sA, const float* __restrict__ sB,
                             float* __restrict__ Hin) {
  const int ch = blockIdx.x * 256 + threadIdx.x;
  float h = 0.0f;
  for (int c = 0; c < NCHUNK; ++c) {
    Hin[c * NCH + ch] = h;
    h = fmaf(sA[c * NCH + ch], h, sB[c * NCH + ch]);
  }
}

// ---------------- phase 3: apply (in place over Barr == d_out) ----------------
__global__ void scan3_kernel(const float* __restrict__ Aarr, const float* __restrict__ Hin,
                             float* __restrict__ y) {
  const int ch = blockIdx.x * 256 + threadIdx.x;
  const int c  = blockIdx.y;
  const int b  = ch >> 10, d = ch & 1023;
  size_t idx = ((size_t)b * SLEN + (size_t)c * CLEN) * DDIM + d;
  float h = Hin[c * NCH + ch];
  #pragma unroll 4
  for (int s = 0; s < CLEN; ++s) {
    const float a  = Aarr[idx];
    const float bb = y[idx];
    h = fmaf(a, h, bb);
    y[idx] = h;
    idx += DDIM;
  }
}

extern "C" void kernel_launch(void* const* d_in, const int* in_sizes, int n_in,
                              void* d_out, int out_size, void* d_ws, size_t ws_size,
                              hipStream_t stream) {
  const float* x   = (const float*)d_in[0];
  const float* Wa  = (const float*)d_in[1];
  const float* Wx  = (const float*)d_in[2];
  const float* ba  = (const float*)d_in[3];
  const float* bx  = (const float*)d_in[4];
  const float* Lam = (const float*)d_in[5];
  float* y = (float*)d_out;

  // workspace layout (bytes): needs 108,007,424 total
  if (ws_size < 108007424ULL) return;  // insufficient scratch; fail cleanly
  char* ws = (char*)d_ws;
  float* Aarr = (float*)(ws);                    // 64 MB: decay a
  bf16*  xb   = (bf16*)(ws + 67108864);          // 32 MB: x bf16, tile-swizzled
  bf16*  wab  = (bf16*)(ws + 100663296);         //  2 MB, tile-swizzled
  bf16*  wxb  = (bf16*)(ws + 102760448);         //  2 MB, tile-swizzled
  float* klam = (float*)(ws + 104857600);        //  4 KB
  float* sA   = (float*)(ws + 104861696);        //  1 MB
  float* sB   = (float*)(ws + 105910272);        //  1 MB
  float* Hin  = (float*)(ws + 106958848);        //  1 MB
  float* Barr = y;                               // b lives in d_out, transformed in place

  cast_swz_kernel<<<(MROWS/32)*(KDIM/32)*128/256, 256, 0, stream>>>(x,  xb);
  cast_swz_kernel<<<(DDIM/32)*(KDIM/32)*128/256, 256, 0, stream>>>(Wa, wab);
  cast_swz_kernel<<<(DDIM/32)*(KDIM/32)*128/256, 256, 0, stream>>>(Wx, wxb);
  klam_kernel<<<DDIM/256, 256, 0, stream>>>(Lam, klam);

  // 2048 blocks: (M/128) * (N/64) = 128 * 16
  gemm_gates_kernel<<<2048, 256, 0, stream>>>(xb, wab, wxb, ba, bx, klam, Aarr, Barr);

  dim3 sgrid(NCH/256, NCHUNK);
  scan1_kernel<<<sgrid, 256, 0, stream>>>(Aarr, Barr, sA, sB);
  scan2_kernel<<<NCH/256, 256, 0, stream>>>(sA, sB, Hin);
  scan3_kernel<<<sgrid, 256, 0, stream>>>(Aarr, Hin, y);
}